// Round 17
// baseline (173.715 us; speedup 1.0000x reference)
//
#include <hip/hip_runtime.h>
#include <hip/hip_fp16.h>
#include <math.h>

#define NB   16     // batch
#define IMG  128    // input image side
#define NANG 300
#define NDET 300
#define WB   148    // canvas live box: x,y in [76,224)
#define ASCALE 32.0f            // fp8 storage scale for attenuation blur
#define ACOEF  (2.0f * 0.01f / ASCALE)   // 6.25e-4 : exp coefficient on stored sumA

typedef float v2f __attribute__((ext_vector_type(2)));

// Gaussian taps: sigma_img -> 2^(-d^2/2); sigma_att -> 2^(-d^2/8). f64 normalize, f32 cast.
__device__ __constant__ float KE[9] = {
  (float)(0.00390625            / 3.0104144100214136),
  (float)(0.04419417382415922   / 3.0104144100214136),
  (float)(0.25                  / 3.0104144100214136),
  (float)(0.7071067811865476    / 3.0104144100214136),
  (float)(1.0                   / 3.0104144100214136),
  (float)(0.7071067811865476    / 3.0104144100214136),
  (float)(0.25                  / 3.0104144100214136),
  (float)(0.04419417382415922   / 3.0104144100214136),
  (float)(0.00390625            / 3.0104144100214136)
};
__device__ __constant__ float KA[17] = {
  (float)(0.00390625            / 6.019333926786741),
  (float)(0.014328188175072987  / 6.019333926786741),
  (float)(0.04419417382415922   / 6.019333926786741),
  (float)(0.11462550540058389   / 6.019333926786741),
  (float)(0.25                  / 6.019333926786741),
  (float)(0.4585020216023356    / 6.019333926786741),
  (float)(0.7071067811865476    / 6.019333926786741),
  (float)(0.9170040432046712    / 6.019333926786741),
  (float)(1.0                   / 6.019333926786741),
  (float)(0.9170040432046712    / 6.019333926786741),
  (float)(0.7071067811865476    / 6.019333926786741),
  (float)(0.4585020216023356    / 6.019333926786741),
  (float)(0.25                  / 6.019333926786741),
  (float)(0.11462550540058389   / 6.019333926786741),
  (float)(0.04419417382415922   / 6.019333926786741),
  (float)(0.014328188175072987  / 6.019333926786741),
  (float)(0.00390625            / 6.019333926786741)
};

// K1: fused pad+blur -> fp8 quad canvas over the live box [76,224)^2.
// Q8[y'][x'][b] = uint2{ E00|E01<<8|E10<<16|E11<<24 , A00|A01<<8|A10<<16|A11<<24 }
// (fp8 e4m3 via HW cvt; suffix (r,c) = (y+r, x+c); A stored as ASCALE*A_blur).
// Whole 2x2 bilinear footprint of both images in ONE 8-B load for k_radon.
// Canvas = 148*148*16*8 B = 2.80 MB -> per-XCD L2 resident.
__global__ void k_prep(const float* __restrict__ img, const float* __restrict__ att,
                       uint2* __restrict__ Q8) {
  __shared__ float sImg[25 * 25];
  __shared__ float sAtt[33 * 33];
  __shared__ float sEi[25 * 17];
  __shared__ float sAi[33 * 17];

  int tid = threadIdx.x;
  int tx = tid & 15, ty = tid >> 4;
  int X0 = blockIdx.x * 16;
  int Y0 = blockIdx.y * 16;
  int b  = blockIdx.z;
  const float* imb = img + b * IMG * IMG;
  const float* atb = att + b * IMG * IMG;
  for (int t = tid; t < 625; t += 256) {
    int r = t / 25, c = t - r * 25;
    int ir = Y0 - 14 + r, ic = X0 - 14 + c;
    bool v = (ir >= 0) & (ir < IMG) & (ic >= 0) & (ic < IMG);
    sImg[t] = v ? imb[ir * IMG + ic] : 0.f;
  }
  for (int t = tid; t < 1089; t += 256) {
    int r = t / 33, c = t - r * 33;
    int ir = Y0 - 18 + r, ic = X0 - 18 + c;
    bool v = (ir >= 0) & (ir < IMG) & (ic >= 0) & (ic < IMG);
    sAtt[t] = v ? atb[ir * IMG + ic] : 0.f;
  }
  __syncthreads();
  for (int t = tid; t < 425; t += 256) {
    int r = t / 17, c = t - r * 17;
    float acc = 0.f;
#pragma unroll
    for (int d = 0; d < 9; ++d) acc = fmaf(KE[d], sImg[r * 25 + c + d], acc);
    sEi[t] = acc;
  }
  for (int t = tid; t < 561; t += 256) {
    int r = t / 17, c = t - r * 17;
    float acc = 0.f;
#pragma unroll
    for (int d = 0; d < 17; ++d) acc = fmaf(KA[d], sAtt[r * 33 + c + d], acc);
    sAi[t] = acc;
  }
  __syncthreads();
  int xc = X0 + tx, yc = Y0 + ty;
  if (xc >= WB || yc >= WB) return;
  float E00 = 0.f, E01 = 0.f, E10 = 0.f, E11 = 0.f;
  float A00 = 0.f, A01 = 0.f, A10 = 0.f, A11 = 0.f;
#pragma unroll
  for (int d = 0; d < 9; ++d) {
    float k = KE[d];
    E00 = fmaf(k, sEi[(ty + d) * 17 + tx],     E00);
    E01 = fmaf(k, sEi[(ty + d) * 17 + tx + 1], E01);
    E10 = fmaf(k, sEi[(ty + 1 + d) * 17 + tx],     E10);
    E11 = fmaf(k, sEi[(ty + 1 + d) * 17 + tx + 1], E11);
  }
#pragma unroll
  for (int d = 0; d < 17; ++d) {
    float k = KA[d];
    A00 = fmaf(k, sAi[(ty + d) * 17 + tx],     A00);
    A01 = fmaf(k, sAi[(ty + d) * 17 + tx + 1], A01);
    A10 = fmaf(k, sAi[(ty + 1 + d) * 17 + tx],     A10);
    A11 = fmaf(k, sAi[(ty + 1 + d) * 17 + tx + 1], A11);
  }
  int ew = __builtin_amdgcn_cvt_pk_fp8_f32(E00, E01, 0, false);
  ew     = __builtin_amdgcn_cvt_pk_fp8_f32(E10, E11, ew, true);
  int aw = __builtin_amdgcn_cvt_pk_fp8_f32(ASCALE * A00, ASCALE * A01, 0, false);
  aw     = __builtin_amdgcn_cvt_pk_fp8_f32(ASCALE * A10, ASCALE * A11, aw, true);
  Q8[(yc * WB + xc) * NB + b] = make_uint2((unsigned)ew, (unsigned)aw);
}

// K2: radon (LDS coordinate pipeline, r12-validated) on the fp8 canvas + block-
// local fused detector blur (r16-validated). Block = 384 thr = 24 jrow x 16 b
// (6 waves): 20-j output strip + 2-j halo each side -> dblur needs only in-block
// S (LDS); 15 blocks/angle; 5 blocks/CU (30 waves) restores occupancy vs r16.
// Per 16-sample chunk: Phase A computes coords + float4 bilinear weights for a
// DISTINCT (j,i) per lane -> per-wave LDS (wave-ordered; wave_barrier = fence);
// Phase B: broadcast ds_read (off b32 + weights b128) + ONE 8-B load + 4 cvt_pk
// f32<-fp8 + 8 fma per sample. Coordinate clamp px,py->[76.5,222.0] before
// floor: identity in-chord; clamped samples hit all-zero rows/cols -> exact 0.
__global__ void __launch_bounds__(384)
k_radon(const uint2* __restrict__ P, const float* __restrict__ scale,
        float* __restrict__ out) {
  __shared__ unsigned sOff[24 * 17];
  __shared__ float4   sW[24 * 17];
  __shared__ float    sS[24 * 17];

  int t = threadIdx.x;
  int b    = t & 15;
  int jrow = t >> 4;                    // 0..23
  int a  = blockIdx.y;
  int jstart = blockIdx.x * 20 - 2;     // block covers j in [jstart, jstart+24)
  int j  = jstart + jrow;
  bool jvalid = (unsigned)j < (unsigned)NDET;

  float th = (float)a * (float)(3.14159265358979323846 / 299.0);
  float c = cosf(th), s = sinf(th);
  float xj = fmaf((float)j, (float)(2.0 / 299.0), -1.0f);
  float pb = fmaf(c,  xj, 1.0f) * 149.5f - 149.5f * s;
  float qb = fmaf(-s, xj, 1.0f) * 149.5f - 149.5f * c;
  const float L = 76.5f, H = 222.5f;
  float lo = 0.f, hi = jvalid ? 299.0f : -1.0f;
  if (s > 1e-6f) {
    float inv = 1.0f / s;
    lo = fmaxf(lo, (L - pb) * inv); hi = fminf(hi, (H - pb) * inv);
  } else if (pb < L || pb > H) { hi = -1.f; }
  if (fabsf(c) > 1e-6f) {
    float inv = 1.0f / c;
    float t0 = (L - qb) * inv, t1 = (H - qb) * inv;
    lo = fmaxf(lo, fminf(t0, t1)); hi = fminf(hi, fmaxf(t0, t1));
  } else if (qb < L || qb > H) { hi = -1.f; }

  // wave-uniform union bounds over this wave's 4 j's (empty chords: lo=0, hi=-1)
  float lo_w = fminf(lo, __shfl_xor(lo, 16));
  lo_w = fminf(lo_w, __shfl_xor(lo_w, 32));
  float hi_w = fmaxf(hi, __shfl_xor(hi, 16));
  hi_w = fmaxf(hi_w, __shfl_xor(hi_w, 32));
  int i0w  = __builtin_amdgcn_readfirstlane((int)floorf(fmaxf(lo_w, 0.f)));
  int ihiw = __builtin_amdgcn_readfirstlane((int)floorf(hi_w));

  unsigned* offW = &sOff[jrow * 17 + b];
  float4*   wW   = &sW[jrow * 17 + b];
  const unsigned* offR = &sOff[jrow * 17];
  const float4*   wR   = &sW[jrow * 17];
  const char* Pcb = (const char*)P + b * 8;
  const int PIXBASE = -76 * 149 * 128;  // pixel stride 128 B (16 b x 8 B)

  float sE0 = 0.f, sE1 = 0.f, sA0 = 0.f, sA1 = 0.f;
  float fib = (float)i0w + (float)b;

  for (int ib = i0w; ib <= ihiw; ib += 16, fib += 16.f) {
    // Phase A: this lane computes sample (j, ib + b)
    {
      float px = fmaf(fib, s, pb);
      float py = fmaf(fib, c, qb);
      px = fminf(fmaxf(px, 76.5f), 222.0f);   // exact-zero clamp (see header)
      py = fminf(fmaxf(py, 76.5f), 222.0f);
      float x0f = floorf(px), y0f = floorf(py);
      float wx = px - x0f, wy = py - y0f;
      int idx = (int)fmaf(y0f, (float)WB, x0f);
      float omx = 1.0f - wx, omy = 1.0f - wy;
      *offW = (unsigned)((idx << 7) + PIXBASE);
      *wW   = make_float4(omy * omx, omy * wx, wy * omx, wy * wx);
    }
    __builtin_amdgcn_wave_barrier();
    // Phase B: consume 16 entries, 2 groups of 8 (8 loads in flight)
#pragma unroll
    for (int g = 0; g < 2; ++g) {
      unsigned o[8]; float4 w[8]; uint2 q[8];
#pragma unroll
      for (int u = 0; u < 8; ++u) { o[u] = offR[g * 8 + u]; w[u] = wR[g * 8 + u]; }
#pragma unroll
      for (int u = 0; u < 8; ++u)
        q[u] = *(const uint2*)(Pcb + (int)o[u]);
#pragma unroll
      for (int u = 0; u < 8; ++u) {
        v2f e01 = __builtin_amdgcn_cvt_pk_f32_fp8((int)q[u].x, false);
        v2f e23 = __builtin_amdgcn_cvt_pk_f32_fp8((int)q[u].x, true);
        v2f a01 = __builtin_amdgcn_cvt_pk_f32_fp8((int)q[u].y, false);
        v2f a23 = __builtin_amdgcn_cvt_pk_f32_fp8((int)q[u].y, true);
        sE0 = fmaf(w[u].x, e01.x, fmaf(w[u].y, e01.y, sE0));
        sE1 = fmaf(w[u].z, e23.x, fmaf(w[u].w, e23.y, sE1));
        sA0 = fmaf(w[u].x, a01.x, fmaf(w[u].y, a01.y, sA0));
        sA1 = fmaf(w[u].z, a23.x, fmaf(w[u].w, a23.y, sA1));
      }
    }
    __builtin_amdgcn_wave_barrier();
  }
  {
    float sumE = sE0 + sE1, sumA = sA0 + sA1;
    // invalid-j rows accumulate exactly 0 (clamped coords on zero canvas)
    sS[jrow * 17 + b] = sumE * expf(-ACOEF * sumA);
  }
  __syncthreads();

  // ---- block-local detector blur + scale (20 output j x 16 b = 320 threads) ----
  if (t < 320) {
    int bb = t / 20, jj = t - (t / 20) * 20;
    int jglob = blockIdx.x * 20 + jj;
    if (jglob < NDET) {
      float u = fabsf(c) + fabsf(s);    // bw = 2u (c,s uniform across block)
      float u2 = u * u;
      float e1 = exp2f(-2.0f * u2);
      float e2 = exp2f(-8.0f * u2);
      float norm = 1.0f / (1.0f + 2.0f * (e1 + e2));
      float w2c = norm, w1c = e1 * norm, w0c = e2 * norm;
      float acc = 0.f;
#pragma unroll
      for (int tt = -2; tt <= 2; ++tt) {
        int jr = jglob + tt;
        if (jr < 0) jr = -jr;
        if (jr > 299) jr = 598 - jr;
        int lr = jr - jstart;           // in [0,24) by construction
        float w = (tt == 0) ? w2c : ((tt == 1 || tt == -1) ? w1c : w0c);
        acc = fmaf(w, sS[lr * 17 + bb], acc);
      }
      out[(bb * NANG + a) * NDET + jglob] = acc * scale[bb];
    }
  }
}

extern "C" void kernel_launch(void* const* d_in, const int* in_sizes, int n_in,
                              void* d_out, int out_size, void* d_ws, size_t ws_size,
                              hipStream_t stream) {
  const float* img   = (const float*)d_in[0];
  const float* att   = (const float*)d_in[1];
  const float* scale = (const float*)d_in[2];
  float* out = (float*)d_out;
  float* ws  = (float*)d_ws;

  // ws layout: Q8 148*148*16 uint2 (2.80 MB)
  uint2* Q8 = (uint2*)ws;

  k_prep <<<dim3(10, 10, NB), 256, 0, stream>>>(img, att, Q8);
  k_radon<<<dim3(15, NANG),   384, 0, stream>>>(Q8, scale, out);
}